// Round 6
// baseline (1750.332 us; speedup 1.0000x reference)
//
#include <hip/hip_runtime.h>

// Sinkhorn distance, 8 batches x 2048 points x 2 dims, 50 iters, eps=0.1.
// v7 = v6 (fenceless IC-routed sync: sc0 sc1 loads/stores for duals+flags,
// zero fences, read-only data stays L1/L2-warm) + batch<->block remap.
// v6 used batch=blk&7: with round-robin dispatch both co-resident blocks on
// every CU were the SAME batch -> whole CU idled at every barrier (VALUBusy
// 34%, ~10us/crossing exposed). v7 uses batch=blk>>6: co-resident blocks
// (c, c+256) are batches c>>6 and c>>6+4 -> independent chains drift, each
// block's barrier wait hides under the co-tenant's compute.

#define P 2048
#define NB 8
constexpr float SCALE = 14.426950408889634f; // log2(e) / eps, eps = 0.1
constexpr float INV4S = 1.0f / (4.0f * SCALE);

typedef float vf4 __attribute__((ext_vector_type(4)));

// ws layout (floats):
// 0       jpY   float2[8*2048]   (32768 f)
// 32768   jpX   float2[8*2048]   (32768 f)
// 65536   rowX  float4[8*2048]   (65536 f)
// 131072  rowY  float4[8*2048]   (65536 f)
// 196608  u[16384]
// 212992  v[16384]
// 229376  partial[512]
// 229888  flags: unsigned[512]  — flags[b*64 + i], 256B per batch

__global__ void setup_kernel(const float* __restrict__ x, const float* __restrict__ yy,
                             float2* __restrict__ jpY, float2* __restrict__ jpX,
                             float4* __restrict__ rowX, float4* __restrict__ rowY,
                             float* __restrict__ u, float* __restrict__ v,
                             float* __restrict__ partial, unsigned* __restrict__ flags) {
    const int n = blockIdx.x;
    const int t = threadIdx.x;
    __shared__ float redx[256], redy[256];
    float xm0[8], xm1[8], ym0[8], ym1[8];
    float sx = 0.f, sy = 0.f;
    #pragma unroll
    for (int k = 0; k < 8; ++k) {
        int p = t + 256 * k;
        size_t base = ((size_t)n * P + p) * 2;
        float a0 = x[base + 0];
        float a1 = x[base + 1];
        float b0 = yy[base + 0];
        float b1 = yy[base + 1];
        // mask = (x != -1); applied to BOTH x and y (per reference)
        float m0 = (a0 != -1.0f) ? 1.0f : 0.0f;
        float m1 = (a1 != -1.0f) ? 1.0f : 0.0f;
        a0 *= m0; a1 *= m1; b0 *= m0; b1 *= m1;
        xm0[k] = a0; xm1[k] = a1; ym0[k] = b0; ym1[k] = b1;
        sx = fmaf(a1, a1, sx);
        sy = fmaf(b1, b1, sy);
    }
    redx[t] = sx; redy[t] = sy;
    __syncthreads();
    for (int off = 128; off > 0; off >>= 1) {
        if (t < off) { redx[t] += redx[t + off]; redy[t] += redy[t + off]; }
        __syncthreads();
    }
    const float inv_sx = 1.0f / redx[0];
    const float inv_sy = 1.0f / redy[0];
    #pragma unroll
    for (int k = 0; k < 8; ++k) {
        int p = t + 256 * k;
        float a0 = xm0[k], a1 = xm1[k], b0 = ym0[k], b1 = ym1[k];
        float qx = fmaf(a0, a0, a1 * a1);
        float qy = fmaf(b0, b0, b1 * b1);
        float mu = a1 * a1 * inv_sx;
        float nu = b1 * b1 * inv_sy;
        // B = log2(marginal + 1e-8) + s*|pt|^2 (cancels dropped row constant)
        float Bmu = __builtin_amdgcn_logf(mu + 1e-8f) + SCALE * qx;
        float Bnu = __builtin_amdgcn_logf(nu + 1e-8f) + SCALE * qy;
        size_t idx = (size_t)n * P + p;
        rowX[idx] = make_float4(a0, a1, Bmu, 0.f);
        rowY[idx] = make_float4(b0, b1, Bnu, 0.f);
        jpX[idx] = make_float2(2.f * SCALE * a0, 2.f * SCALE * a1);
        jpY[idx] = make_float2(2.f * SCALE * b0, 2.f * SCALE * b1);
        u[idx] = 0.f;
        v[idx] = 0.f;
    }
    if (n == 0) {
        partial[t] = 0.f; partial[t + 256] = 0.f;
        flags[t] = 0u; flags[t + 256] = 0u;
    }
}

// j <-> (lane, k) mapping: j = lane*32 + k  (lane-contiguous, dwordx4 loads).
__device__ __forceinline__ void load_Y(const vf4* __restrict__ p,
                                       float (&Y0)[32], float (&Y1)[32]) {
    #pragma unroll
    for (int m = 0; m < 16; ++m) {
        vf4 q = p[m];
        Y0[2 * m] = q[0];     Y1[2 * m] = q[1];
        Y0[2 * m + 1] = q[2]; Y1[2 * m + 1] = q[3];
    }
}

// out_i = B_i - log2( sum_j 2^( V_j + Y0_j*x0_i + Y1_j*x1_i ) )
__device__ __forceinline__ float rowsum(const float (&Y0)[32], const float (&Y1)[32],
                                        const float (&V)[32], float x0, float x1) {
    float a0 = 0.f, a1 = 0.f, a2 = 0.f, a3 = 0.f;
    #pragma unroll
    for (int k = 0; k < 32; k += 4) {
        a0 += __builtin_amdgcn_exp2f(fmaf(Y1[k + 0], x1, fmaf(Y0[k + 0], x0, V[k + 0])));
        a1 += __builtin_amdgcn_exp2f(fmaf(Y1[k + 1], x1, fmaf(Y0[k + 1], x0, V[k + 1])));
        a2 += __builtin_amdgcn_exp2f(fmaf(Y1[k + 2], x1, fmaf(Y0[k + 2], x0, V[k + 2])));
        a3 += __builtin_amdgcn_exp2f(fmaf(Y1[k + 3], x1, fmaf(Y0[k + 3], x0, V[k + 3])));
    }
    return (a0 + a1) + (a2 + a3);
}

// Dual read: 8x dwordx4 from the coherent point (sc0 sc1 bypasses the stale
// L1/L2), ONE latency for all 8, no fence needed.
__device__ __forceinline__ void load_duals_coherent(const float* __restrict__ din,
                                                    int lane, vf4 (&dv)[8]) {
    const float* dbase = din + (size_t)lane * 32;
    asm volatile(
        "global_load_dwordx4 %0, %8, off sc0 sc1\n\t"
        "global_load_dwordx4 %1, %8, off offset:16 sc0 sc1\n\t"
        "global_load_dwordx4 %2, %8, off offset:32 sc0 sc1\n\t"
        "global_load_dwordx4 %3, %8, off offset:48 sc0 sc1\n\t"
        "global_load_dwordx4 %4, %8, off offset:64 sc0 sc1\n\t"
        "global_load_dwordx4 %5, %8, off offset:80 sc0 sc1\n\t"
        "global_load_dwordx4 %6, %8, off offset:96 sc0 sc1\n\t"
        "global_load_dwordx4 %7, %8, off offset:112 sc0 sc1\n\t"
        "s_waitcnt vmcnt(0)"
        : "=&v"(dv[0]), "=&v"(dv[1]), "=&v"(dv[2]), "=&v"(dv[3]),
          "=&v"(dv[4]), "=&v"(dv[5]), "=&v"(dv[6]), "=&v"(dv[7])
        : "v"(dbase)
        : "memory");
}

__device__ __forceinline__ void half_phase(const float (&Y0)[32], const float (&Y1)[32],
                                           const float* __restrict__ din,
                                           const float4* __restrict__ rdat,
                                           float* __restrict__ dout,
                                           const int lane, const int rowbase) {
    // V_j = dual_j - Q_j, Q recomputed from Y0,Y1: Q = (Y0^2 + Y1^2)/(4S)
    vf4 dv[8];
    load_duals_coherent(din, lane, dv);
    float V[32];
    #pragma unroll
    for (int k8 = 0; k8 < 8; ++k8) {
        #pragma unroll
        for (int e = 0; e < 4; ++e) {
            int k = k8 * 4 + e;
            float q = fmaf(Y0[k], Y0[k], Y1[k] * Y1[k]);
            V[k] = fmaf(q, -INV4S, dv[k8][e]);
        }
    }
    float acc[8], Bs[8];
    #pragma unroll
    for (int r = 0; r < 8; ++r) {
        float4 rv = rdat[rowbase + r];     // wave-uniform, cached (read-only)
        Bs[r] = rv.z;
        acc[r] = rowsum(Y0, Y1, V, rv.x, rv.y);
    }
    // 8 independent butterflies (pipelined, not 8 serial dependent chains)
    #pragma unroll
    for (int r = 0; r < 8; ++r) {
        float a = acc[r];
        #pragma unroll
        for (int m = 1; m < 64; m <<= 1) a += __shfl_xor(a, m, 64);
        acc[r] = a;
    }
    if (lane == 0) {
        vf4 o0, o1;
        #pragma unroll
        for (int r = 0; r < 4; ++r) {
            o0[r] = Bs[r] - __builtin_amdgcn_logf(acc[r]);
            o1[r] = Bs[r + 4] - __builtin_amdgcn_logf(acc[r + 4]);
        }
        // Store straight to the coherent point; vmcnt drain = this wave's
        // release point (no wbl2: nothing dirty in L2 to publish).
        float* dptr = dout + rowbase;
        asm volatile(
            "global_store_dwordx4 %0, %1, off sc0 sc1\n\t"
            "global_store_dwordx4 %0, %2, off offset:16 sc0 sc1\n\t"
            "s_waitcnt vmcnt(0)"
            :: "v"(dptr), "v"(o0), "v"(o1)
            : "memory");
    }
}

// Arrival: own-slot coherent store (after syncthreads: all waves' coherent
// dual stores already drained). Detection: wave0 polls all 64 flags with one
// per-lane coherent load + __all. No fences anywhere. Deadman ~1.6ms/barrier:
// fails verification visibly, never trips the watchdog.
__device__ __forceinline__ void flag_barrier(unsigned* __restrict__ fl,
                                             int blkin, int wave, int lane,
                                             unsigned ep) {
    __syncthreads();
    if (threadIdx.x == 0) {
        asm volatile("global_store_dword %0, %1, off sc0 sc1"
                     :: "v"(fl + blkin), "v"(ep) : "memory");
    }
    if (wave == 0) {
        const unsigned* fp = fl + lane;
        int guard = 0;
        unsigned f;
        for (;;) {
            asm volatile("global_load_dword %0, %1, off sc0 sc1\n\t"
                         "s_waitcnt vmcnt(0)"
                         : "=&v"(f) : "v"(fp) : "memory");
            if (__all(f >= ep)) break;
            __builtin_amdgcn_s_sleep(4);       // ~0.1us grain: fast detect,
            if (++guard > (1 << 14)) break;    //  polls are plain IC loads
        }
    }
    __syncthreads();
}

// 512 blocks x 256 threads, 2 blocks/CU -> all co-resident (proven v2-v6).
// batch = blk>>6, blkin = blk&63: co-resident CU pair (c, c+256) = batches
// c>>6 and c>>6+4 -> independent chains overlap; a waiting block's SIMDs
// are driven by the other batch's compute.
__global__ __launch_bounds__(256, 2) void sinkhorn_iter_kernel(
        const float2* __restrict__ jpY, const float2* __restrict__ jpX,
        const float4* __restrict__ rowX, const float4* __restrict__ rowY,
        float* __restrict__ u, float* __restrict__ v, unsigned* __restrict__ flags) {
    const int blk = blockIdx.x;
    const int batch = blk >> 6;               // v7: was blk & 7
    const int blkin = blk & 63;               // v7: was blk >> 3
    const int lane = threadIdx.x & 63;
    const int wave = threadIdx.x >> 6;        // 0..3
    const int rowbase = blkin * 32 + wave * 8;

    const vf4* py = (const vf4*)((const float2*)(jpY + (size_t)batch * P) + (size_t)lane * 32);
    const vf4* px = (const vf4*)((const float2*)(jpX + (size_t)batch * P) + (size_t)lane * 32);
    const float4* rX = rowX + (size_t)batch * P;
    const float4* rY = rowY + (size_t)batch * P;
    float* ub = u + (size_t)batch * P;
    float* vb = v + (size_t)batch * P;
    unsigned* fl = flags + (size_t)batch * 64;   // 256B region, own slot fl[blkin]

    float Y0[32], Y1[32];                     // reloaded per phase (L1/L2-warm;
    unsigned ep = 0;                          //  no fences ever evict them)
    for (int it = 0; it < 50; ++it) {
        // ---- u-update: reduce over j (y side), reads v, writes u ----
        load_Y(py, Y0, Y1);
        half_phase(Y0, Y1, vb, rX, ub, lane, rowbase);
        ++ep;
        flag_barrier(fl, blkin, wave, lane, ep);

        // ---- v-update: reduce over i (x side), reads u, writes v ----
        load_Y(px, Y0, Y1);
        half_phase(Y0, Y1, ub, rY, vb, lane, rowbase);
        if (it < 49) {
            ++ep;
            flag_barrier(fl, blkin, wave, lane, ep);
        }
    }
}

// Final: pi = 2^(u~_i + v~_j - s*C_ij), C, and cost partials.
// (kernel boundary makes iter's coherent stores visible to plain loads)
__global__ void final_kernel(const float4* __restrict__ rowX, const float4* __restrict__ rowY,
                             const float* __restrict__ u, const float* __restrict__ v,
                             float* __restrict__ out, float* __restrict__ partial) {
    const int blk = blockIdx.x;
    const int batch = blk & 7;
    const int i = blk >> 3;
    const int t = threadIdx.x;

    const float4 rx = rowX[(size_t)batch * P + i];
    const float ui = u[(size_t)batch * P + i];
    const float x0 = rx.x, x1 = rx.y;

    float* pi_out = out + 8 + (size_t)batch * P * P + (size_t)i * P;
    float* C_out = pi_out + (size_t)NB * P * P;
    const float4* ry = rowY + (size_t)batch * P;
    const float* vv = v + (size_t)batch * P;

    float costacc = 0.f;
    #pragma unroll
    for (int c = 0; c < 2; ++c) {
        const int j0 = c * 1024 + t * 4;
        vf4 vj = *(const vf4*)(vv + j0);
        vf4 Cv, Pv;
        #pragma unroll
        for (int e = 0; e < 4; ++e) {
            float4 q = ry[j0 + e];
            float dx = x0 - q.x;
            float dy = x1 - q.y;
            float Cj = fmaf(dy, dy, dx * dx);
            float pj = __builtin_amdgcn_exp2f(fmaf(Cj, -SCALE, ui + vj[e]));
            Cv[e] = Cj;
            Pv[e] = pj;
            costacc = fmaf(pj, Cj, costacc);
        }
        __builtin_nontemporal_store(Pv, (vf4*)(pi_out + j0));
        __builtin_nontemporal_store(Cv, (vf4*)(C_out + j0));
    }

    #pragma unroll
    for (int m = 1; m < 64; m <<= 1) costacc += __shfl_xor(costacc, m, 64);
    __shared__ float sred[4];
    const int wave = t >> 6, lane = t & 63;
    if (lane == 0) sred[wave] = costacc;
    __syncthreads();
    if (t == 0) {
        float s = sred[0] + sred[1] + sred[2] + sred[3];
        atomicAdd(&partial[batch * 64 + (i & 63)], s);
    }
}

__global__ void costreduce_kernel(const float* __restrict__ partial, float* __restrict__ out) {
    const int t = threadIdx.x; // 512 threads: wave w reduces batch w's 64 slots
    float val = partial[t];
    #pragma unroll
    for (int m = 1; m < 64; m <<= 1) val += __shfl_xor(val, m, 64);
    if ((t & 63) == 0) out[t >> 6] = val;
}

extern "C" void kernel_launch(void* const* d_in, const int* in_sizes, int n_in,
                              void* d_out, int out_size, void* d_ws, size_t ws_size,
                              hipStream_t stream) {
    const float* x = (const float*)d_in[0];
    const float* y = (const float*)d_in[1];
    float* out = (float*)d_out;
    float* ws = (float*)d_ws;

    float2* jpY = (float2*)ws;
    float2* jpX = (float2*)(ws + 32768);
    float4* rowX = (float4*)(ws + 65536);
    float4* rowY = (float4*)(ws + 131072);
    float* u = ws + 196608;
    float* v = ws + 196608 + 16384;
    float* partial = ws + 196608 + 32768;
    unsigned* flags = (unsigned*)(ws + 196608 + 32768 + 512);

    setup_kernel<<<8, 256, 0, stream>>>(x, y, jpY, jpX, rowX, rowY, u, v, partial, flags);
    sinkhorn_iter_kernel<<<512, 256, 0, stream>>>(jpY, jpX, rowX, rowY, u, v, flags);
    final_kernel<<<16384, 256, 0, stream>>>(rowX, rowY, u, v, out, partial);
    costreduce_kernel<<<1, 512, 0, stream>>>(partial, out);
}

// Round 7
// 1053.113 us; speedup vs baseline: 1.6621x; 1.6621x over previous
//
#include <hip/hip_runtime.h>

// Sinkhorn distance, 8 batches x 2048 points x 2 dims, 50 iters, eps=0.1.
// v8: back to multi-launch (hardware inter-kernel sync ~3us beat every
// software barrier: v2-v7 persistent variants all cost 15-20us/phase).
// v1's cost was the per-WAVE 40KB register preamble (320KB/CU/phase from
// L2). v8 stages j-side data once per BLOCK into LDS (24KB: Y0,Y1,V with
// V = dual - Q computed inline), coalesced unit-stride loads, conflict-free
// LDS access (lane j-set = {k*64+lane}), ~70 VGPR, no spin/atomics/fences.

#define P 2048
#define NB 8
constexpr float SCALE = 14.426950408889634f; // log2(e) / eps, eps = 0.1
constexpr float INV4S = 1.0f / (4.0f * SCALE);

typedef float vf4 __attribute__((ext_vector_type(4)));

// ws layout (floats):
// 0       jpY   float2[8*2048]   (32768 f)
// 32768   jpX   float2[8*2048]   (32768 f)
// 65536   rowX  float4[8*2048]   (65536 f)
// 131072  rowY  float4[8*2048]   (65536 f)
// 196608  u[16384]
// 212992  v[16384]
// 229376  partial[512]

__global__ void setup_kernel(const float* __restrict__ x, const float* __restrict__ yy,
                             float2* __restrict__ jpY, float2* __restrict__ jpX,
                             float4* __restrict__ rowX, float4* __restrict__ rowY,
                             float* __restrict__ u, float* __restrict__ v,
                             float* __restrict__ partial) {
    const int n = blockIdx.x;
    const int t = threadIdx.x;
    __shared__ float redx[256], redy[256];
    float xm0[8], xm1[8], ym0[8], ym1[8];
    float sx = 0.f, sy = 0.f;
    #pragma unroll
    for (int k = 0; k < 8; ++k) {
        int p = t + 256 * k;
        size_t base = ((size_t)n * P + p) * 2;
        float a0 = x[base + 0];
        float a1 = x[base + 1];
        float b0 = yy[base + 0];
        float b1 = yy[base + 1];
        // mask = (x != -1); applied to BOTH x and y (per reference)
        float m0 = (a0 != -1.0f) ? 1.0f : 0.0f;
        float m1 = (a1 != -1.0f) ? 1.0f : 0.0f;
        a0 *= m0; a1 *= m1; b0 *= m0; b1 *= m1;
        xm0[k] = a0; xm1[k] = a1; ym0[k] = b0; ym1[k] = b1;
        sx = fmaf(a1, a1, sx);
        sy = fmaf(b1, b1, sy);
    }
    redx[t] = sx; redy[t] = sy;
    __syncthreads();
    for (int off = 128; off > 0; off >>= 1) {
        if (t < off) { redx[t] += redx[t + off]; redy[t] += redy[t + off]; }
        __syncthreads();
    }
    const float inv_sx = 1.0f / redx[0];
    const float inv_sy = 1.0f / redy[0];
    #pragma unroll
    for (int k = 0; k < 8; ++k) {
        int p = t + 256 * k;
        float a0 = xm0[k], a1 = xm1[k], b0 = ym0[k], b1 = ym1[k];
        float qx = fmaf(a0, a0, a1 * a1);
        float qy = fmaf(b0, b0, b1 * b1);
        float mu = a1 * a1 * inv_sx;
        float nu = b1 * b1 * inv_sy;
        // B = log2(marginal + 1e-8) + s*|pt|^2 (cancels dropped row constant)
        float Bmu = __builtin_amdgcn_logf(mu + 1e-8f) + SCALE * qx;
        float Bnu = __builtin_amdgcn_logf(nu + 1e-8f) + SCALE * qy;
        size_t idx = (size_t)n * P + p;
        rowX[idx] = make_float4(a0, a1, Bmu, 0.f);
        rowY[idx] = make_float4(b0, b1, Bnu, 0.f);
        jpX[idx] = make_float2(2.f * SCALE * a0, 2.f * SCALE * a1);
        jpY[idx] = make_float2(2.f * SCALE * b0, 2.f * SCALE * b1);
        u[idx] = 0.f;
        v[idx] = 0.f;
    }
    if (n == 0) { partial[t] = 0.f; partial[t + 256] = 0.f; }
}

// One half Sinkhorn iteration:
//   out_i = B_i - log2( sum_j 2^( V_j + Y0_j*x0_i + Y1_j*x1_i ) )
// Grid 512 x 256, batch = blk&7 (XCD-local data). Block stages all 2048
// j-entries into LDS cooperatively (thread t handles j = t + 256*c, fully
// coalesced), then each wave computes 8 rows; lane's j-set = {k*64+lane}
// (2 lanes/bank LDS reads = conflict-free), wave butterfly completes rows.
__global__ __launch_bounds__(256, 2) void halfpass_kernel(
        const float2* __restrict__ jp, const float* __restrict__ jdual,
        const float4* __restrict__ rowdat, float* __restrict__ outdual) {
    const int blk = blockIdx.x;
    const int batch = blk & 7;
    const int blkin = blk >> 3;               // 0..63
    const int t = threadIdx.x;
    const int lane = t & 63;
    const int wave = t >> 6;                  // 0..3

    __shared__ float Y0s[P];
    __shared__ float Y1s[P];
    __shared__ float Vs[P];

    // ---- cooperative stage: 48KB/CU/phase from L2 instead of v1's 320KB ----
    {
        const float2* jpb = jp + (size_t)batch * P;
        const float* ddb = jdual + (size_t)batch * P;
        #pragma unroll
        for (int c = 0; c < 8; ++c) {
            int j = t + 256 * c;              // unit-stride across threads
            float2 p = jpb[j];
            float d = ddb[j];
            float q = fmaf(p.x, p.x, p.y * p.y);   // = 4*S^2*|y|^2
            Y0s[j] = p.x;
            Y1s[j] = p.y;
            Vs[j] = fmaf(q, -INV4S, d);            // dual - S*|y|^2
        }
    }
    __syncthreads();

    // ---- compute: wave owns 8 rows ----
    const int rowbase = blkin * 32 + wave * 8;
    const float4* rd = rowdat + (size_t)batch * P;
    float x0[8], x1[8], Bs[8], acc[8];
    #pragma unroll
    for (int r = 0; r < 8; ++r) {
        float4 rv = rd[rowbase + r];          // wave-uniform -> scalar load
        x0[r] = rv.x; x1[r] = rv.y; Bs[r] = rv.z;
        acc[r] = 0.f;
    }
    #pragma unroll
    for (int g = 0; g < 8; ++g) {             // chunks of 4 k (j = k*64+lane)
        float cy0[4], cy1[4], cv[4];
        #pragma unroll
        for (int e = 0; e < 4; ++e) {
            int j = (4 * g + e) * 64 + lane;  // one ds base + imm offsets
            cy0[e] = Y0s[j];
            cy1[e] = Y1s[j];
            cv[e] = Vs[j];
        }
        #pragma unroll
        for (int r = 0; r < 8; ++r) {
            #pragma unroll
            for (int e = 0; e < 4; ++e)
                acc[r] += __builtin_amdgcn_exp2f(
                    fmaf(cy1[e], x1[r], fmaf(cy0[e], x0[r], cv[e])));
        }
    }
    // 8 independent butterflies (pipelined)
    #pragma unroll
    for (int r = 0; r < 8; ++r) {
        float a = acc[r];
        #pragma unroll
        for (int m = 1; m < 64; m <<= 1) a += __shfl_xor(a, m, 64);
        acc[r] = a;
    }
    if (lane == 0) {
        vf4 o0, o1;
        #pragma unroll
        for (int r = 0; r < 4; ++r) {
            o0[r] = Bs[r] - __builtin_amdgcn_logf(acc[r]);
            o1[r] = Bs[r + 4] - __builtin_amdgcn_logf(acc[r + 4]);
        }
        float* op = outdual + (size_t)batch * P + rowbase;
        *(vf4*)op = o0;
        *(vf4*)(op + 4) = o1;
    }
}

// Final: pi = 2^(u~_i + v~_j - s*C_ij), C, and cost partials.
__global__ void final_kernel(const float4* __restrict__ rowX, const float4* __restrict__ rowY,
                             const float* __restrict__ u, const float* __restrict__ v,
                             float* __restrict__ out, float* __restrict__ partial) {
    const int blk = blockIdx.x;
    const int batch = blk & 7;
    const int i = blk >> 3;
    const int t = threadIdx.x;

    const float4 rx = rowX[(size_t)batch * P + i];
    const float ui = u[(size_t)batch * P + i];
    const float x0 = rx.x, x1 = rx.y;

    float* pi_out = out + 8 + (size_t)batch * P * P + (size_t)i * P;
    float* C_out = pi_out + (size_t)NB * P * P;
    const float4* ry = rowY + (size_t)batch * P;
    const float* vv = v + (size_t)batch * P;

    float costacc = 0.f;
    #pragma unroll
    for (int c = 0; c < 2; ++c) {
        const int j0 = c * 1024 + t * 4;
        vf4 vj = *(const vf4*)(vv + j0);
        vf4 Cv, Pv;
        #pragma unroll
        for (int e = 0; e < 4; ++e) {
            float4 q = ry[j0 + e];
            float dx = x0 - q.x;
            float dy = x1 - q.y;
            float Cj = fmaf(dy, dy, dx * dx);
            float pj = __builtin_amdgcn_exp2f(fmaf(Cj, -SCALE, ui + vj[e]));
            Cv[e] = Cj;
            Pv[e] = pj;
            costacc = fmaf(pj, Cj, costacc);
        }
        __builtin_nontemporal_store(Pv, (vf4*)(pi_out + j0));
        __builtin_nontemporal_store(Cv, (vf4*)(C_out + j0));
    }

    #pragma unroll
    for (int m = 1; m < 64; m <<= 1) costacc += __shfl_xor(costacc, m, 64);
    __shared__ float sred[4];
    const int wave = t >> 6, lane = t & 63;
    if (lane == 0) sred[wave] = costacc;
    __syncthreads();
    if (t == 0) {
        float s = sred[0] + sred[1] + sred[2] + sred[3];
        atomicAdd(&partial[batch * 64 + (i & 63)], s);
    }
}

__global__ void costreduce_kernel(const float* __restrict__ partial, float* __restrict__ out) {
    const int t = threadIdx.x; // 512 threads: wave w reduces batch w's 64 slots
    float val = partial[t];
    #pragma unroll
    for (int m = 1; m < 64; m <<= 1) val += __shfl_xor(val, m, 64);
    if ((t & 63) == 0) out[t >> 6] = val;
}

extern "C" void kernel_launch(void* const* d_in, const int* in_sizes, int n_in,
                              void* d_out, int out_size, void* d_ws, size_t ws_size,
                              hipStream_t stream) {
    const float* x = (const float*)d_in[0];
    const float* y = (const float*)d_in[1];
    float* out = (float*)d_out;
    float* ws = (float*)d_ws;

    float2* jpY = (float2*)ws;
    float2* jpX = (float2*)(ws + 32768);
    float4* rowX = (float4*)(ws + 65536);
    float4* rowY = (float4*)(ws + 131072);
    float* u = ws + 196608;
    float* v = ws + 196608 + 16384;
    float* partial = ws + 196608 + 32768;

    setup_kernel<<<8, 256, 0, stream>>>(x, y, jpY, jpX, rowX, rowY, u, v, partial);
    for (int it = 0; it < 50; ++it) {
        // u-update: reduce over j (y side), reads v, writes u
        halfpass_kernel<<<512, 256, 0, stream>>>(jpY, v, rowX, u);
        // v-update: reduce over i (x side), reads u, writes v
        halfpass_kernel<<<512, 256, 0, stream>>>(jpX, u, rowY, v);
    }
    final_kernel<<<16384, 256, 0, stream>>>(rowX, rowY, u, v, out, partial);
    costreduce_kernel<<<1, 512, 0, stream>>>(partial, out);
}